// Round 1
// baseline (898.162 us; speedup 1.0000x reference)
//
#include <hip/hip_runtime.h>

#define D 128
#define BM 64
#define SB 256
#define SI 8
#define SCHUNK (SB * SI)

// ---------------- degree / CSR build ----------------

__global__ void count_kernel(const int* __restrict__ dst, int* __restrict__ cnt, int E) {
  int e = blockIdx.x * blockDim.x + threadIdx.x;
  if (e < E) atomicAdd(&cnt[dst[e]], 1);
}

__global__ void dis_kernel(const int* __restrict__ cnt, float* __restrict__ dis, int N) {
  int i = blockIdx.x * blockDim.x + threadIdx.x;
  if (i < N) dis[i] = rsqrtf((float)(cnt[i] + 1));  // +1 self-loop; deg>=1 always
}

__global__ void scan1_kernel(const int* __restrict__ cnt, int* __restrict__ off,
                             int* __restrict__ bsum, int n) {
  __shared__ int tsum[SB];
  int tid = threadIdx.x;
  int base = blockIdx.x * SCHUNK;
  int v[SI];
  int s = 0;
#pragma unroll
  for (int i = 0; i < SI; i++) {
    int idx = base + tid * SI + i;
    v[i] = (idx < n) ? cnt[idx] : 0;
    s += v[i];
  }
  tsum[tid] = s;
  __syncthreads();
  for (int o = 1; o < SB; o <<= 1) {
    int t = (tid >= o) ? tsum[tid - o] : 0;
    __syncthreads();
    tsum[tid] += t;
    __syncthreads();
  }
  int run = tsum[tid] - s;  // exclusive prefix for this thread's chunk
#pragma unroll
  for (int i = 0; i < SI; i++) {
    int idx = base + tid * SI + i;
    if (idx < n) off[idx] = run;
    run += v[i];
  }
  if (tid == SB - 1) bsum[blockIdx.x] = tsum[tid];
}

__global__ void scan2_kernel(int* bsum, int nb) {
  if (threadIdx.x == 0 && blockIdx.x == 0) {
    int run = 0;
    for (int b = 0; b < nb; b++) { int t = bsum[b]; bsum[b] = run; run += t; }
  }
}

__global__ void scan3_kernel(int* __restrict__ off, const int* __restrict__ bsum,
                             int n, int total) {
  int i = blockIdx.x * blockDim.x + threadIdx.x;
  if (i < n) off[i] += bsum[i / SCHUNK];
  if (i == 0) off[n] = total;
}

__global__ void fill_kernel(const int* __restrict__ src, const int* __restrict__ dst,
                            const int* __restrict__ off, int* __restrict__ cursor,
                            int* __restrict__ esrc, float* __restrict__ enorm,
                            const float* __restrict__ dis, int E) {
  int e = blockIdx.x * blockDim.x + threadIdx.x;
  if (e >= E) return;
  int s = src[e], d = dst[e];
  int p = off[d] + atomicAdd(&cursor[d], 1);
  esrc[p] = s;
  enorm[p] = dis[s] * dis[d];
}

// ---------------- fp32 GEMM: C[N x 128] = A[N x 128] @ W[128 x 128] ----------------

__global__ __launch_bounds__(256) void gemm_kernel(const float* __restrict__ A,
                                                   const float* __restrict__ W,
                                                   float* __restrict__ C, int N) {
  __shared__ float As[BM][D + 4];   // pad 132: rotated banks, float4-aligned rows
  __shared__ float Wt[D][D + 4];    // Wt[c][k] = W[k][c]
  int tid = threadIdx.x;
  int row0 = blockIdx.x * BM;
#pragma unroll
  for (int i = 0; i < 64; i++) {
    int idx = i * 256 + tid;
    Wt[idx & 127][idx >> 7] = W[idx];
  }
#pragma unroll
  for (int i = 0; i < 32; i++) {
    int idx = i * 256 + tid;
    int r = idx >> 7, k = idx & 127;
    int g = row0 + r;
    As[r][k] = (g < N) ? A[(size_t)g * D + k] : 0.f;
  }
  __syncthreads();
  int col = tid & 127;
  int rb = tid >> 7;  // 0/1 -> row half
  float acc[32];
#pragma unroll
  for (int r = 0; r < 32; r++) acc[r] = 0.f;
  for (int k4 = 0; k4 < D; k4 += 4) {
    float4 w = *(const float4*)&Wt[col][k4];
#pragma unroll
    for (int r = 0; r < 32; r++) {
      float4 a = *(const float4*)&As[rb * 32 + r][k4];  // wave-uniform broadcast
      acc[r] += a.x * w.x + a.y * w.y + a.z * w.z + a.w * w.w;
    }
  }
#pragma unroll
  for (int r = 0; r < 32; r++) {
    int g = row0 + rb * 32 + r;
    if (g < N) C[(size_t)g * D + col] = acc[r];
  }
}

// ---------------- aggregation: one wave per node, gather CSR in-edges ----------------

__global__ __launch_bounds__(256) void agg_kernel(const float* __restrict__ h,
                                                  const float* __restrict__ dis,
                                                  const int* __restrict__ off,
                                                  const int* __restrict__ esrc,
                                                  const float* __restrict__ enorm,
                                                  const float* __restrict__ bias,
                                                  float* __restrict__ out, int N, int doRelu) {
  int node = blockIdx.x * 4 + (threadIdx.x >> 6);
  if (node >= N) return;
  int lane = threadIdx.x & 63;
  int j0 = off[node], j1 = off[node + 1];
  float2 acc = make_float2(0.f, 0.f);
  for (int j = j0; j < j1; j++) {
    int s = esrc[j];
    float wgt = enorm[j];
    float2 hv = *(const float2*)&h[(size_t)s * D + lane * 2];
    acc.x += hv.x * wgt;
    acc.y += hv.y * wgt;
  }
  float ds = dis[node];
  float sw = ds * ds;  // self-loop norm
  float2 hv = *(const float2*)&h[(size_t)node * D + lane * 2];
  acc.x += hv.x * sw;
  acc.y += hv.y * sw;
  acc.x += bias[lane * 2];
  acc.y += bias[lane * 2 + 1];
  if (doRelu) { acc.x = fmaxf(acc.x, 0.f); acc.y = fmaxf(acc.y, 0.f); }
  *(float2*)&out[(size_t)node * D + lane * 2] = acc;
}

// ---------------- launch ----------------

extern "C" void kernel_launch(void* const* d_in, const int* in_sizes, int n_in,
                              void* d_out, int out_size, void* d_ws, size_t ws_size,
                              hipStream_t stream) {
  const float* x  = (const float*)d_in[0];
  const int*   ei = (const int*)d_in[1];
  const float* W1 = (const float*)d_in[2];
  const float* b1 = (const float*)d_in[3];
  const float* W2 = (const float*)d_in[4];
  const float* b2 = (const float*)d_in[5];
  const float* W3 = (const float*)d_in[6];
  const float* b3 = (const float*)d_in[7];
  int N = in_sizes[0] / D;
  int E = in_sizes[1] / 2;
  const int* srcp = ei;
  const int* dstp = ei + E;

  char* wp = (char*)d_ws;
  auto carve = [&](size_t bytes) {
    void* p = (void*)wp;
    wp += (bytes + 255) & ~(size_t)255;
    return p;
  };
  int*   cnt    = (int*)carve((size_t)N * 4);
  int*   cursor = (int*)carve((size_t)N * 4);
  int*   off    = (int*)carve((size_t)(N + 1) * 4);
  int*   bsum   = (int*)carve(256 * 4);
  float* dis    = (float*)carve((size_t)N * 4);
  int*   esrc   = (int*)carve((size_t)E * 4);
  float* enorm  = (float*)carve((size_t)E * 4);
  float* h      = (float*)carve((size_t)N * D * 4);

  hipMemsetAsync(cnt, 0, (size_t)N * 4, stream);
  hipMemsetAsync(cursor, 0, (size_t)N * 4, stream);

  const int tb = 256;
  count_kernel<<<(E + tb - 1) / tb, tb, 0, stream>>>(dstp, cnt, E);
  dis_kernel<<<(N + tb - 1) / tb, tb, 0, stream>>>(cnt, dis, N);
  int nb = (N + SCHUNK - 1) / SCHUNK;
  scan1_kernel<<<nb, SB, 0, stream>>>(cnt, off, bsum, N);
  scan2_kernel<<<1, 64, 0, stream>>>(bsum, nb);
  scan3_kernel<<<(N + tb - 1) / tb, tb, 0, stream>>>(off, bsum, N, E);
  fill_kernel<<<(E + tb - 1) / tb, tb, 0, stream>>>(srcp, dstp, off, cursor, esrc, enorm, dis, E);

  int gb = (N + BM - 1) / BM;
  float* out = (float*)d_out;
  gemm_kernel<<<gb, 256, 0, stream>>>(x, W1, h, N);
  agg_kernel<<<(N + 3) / 4, 256, 0, stream>>>(h, dis, off, esrc, enorm, b1, out, N, 1);
  gemm_kernel<<<gb, 256, 0, stream>>>(out, W2, h, N);
  agg_kernel<<<(N + 3) / 4, 256, 0, stream>>>(h, dis, off, esrc, enorm, b2, out, N, 1);
  gemm_kernel<<<gb, 256, 0, stream>>>(out, W3, h, N);
  agg_kernel<<<(N + 3) / 4, 256, 0, stream>>>(h, dis, off, esrc, enorm, b3, out, N, 0);
}

// Round 2
// 532.168 us; speedup vs baseline: 1.6877x; 1.6877x over previous
//
#include <hip/hip_runtime.h>

#define D 128
#define SB 256
#define SI 8
#define SCHUNK (SB * SI)

typedef __attribute__((ext_vector_type(8))) short bf16x8;
typedef __attribute__((ext_vector_type(4))) float f32x4;
typedef unsigned int uint32;
typedef unsigned short ushort;

__device__ __forceinline__ ushort bf16rne(float f) {
  uint32 u = __float_as_uint(f);
  uint32 r = u + 0x7FFFu + ((u >> 16) & 1u);
  return (ushort)(r >> 16);
}

// ---------------- degree / CSR build ----------------

__global__ void count_kernel(const int* __restrict__ dst, int* __restrict__ cnt, int E) {
  int e = blockIdx.x * blockDim.x + threadIdx.x;
  if (e < E) atomicAdd(&cnt[dst[e]], 1);
}

__global__ void dis_kernel(const int* __restrict__ cnt, float* __restrict__ dis, int N) {
  int i = blockIdx.x * blockDim.x + threadIdx.x;
  if (i < N) dis[i] = rsqrtf((float)(cnt[i] + 1));  // +1 self-loop
}

__global__ void scan1_kernel(const int* __restrict__ cnt, int* __restrict__ off,
                             int* __restrict__ bsum, int n) {
  __shared__ int tsum[SB];
  int tid = threadIdx.x;
  int base = blockIdx.x * SCHUNK;
  int v[SI];
  int s = 0;
#pragma unroll
  for (int i = 0; i < SI; i++) {
    int idx = base + tid * SI + i;
    v[i] = (idx < n) ? cnt[idx] : 0;
    s += v[i];
  }
  tsum[tid] = s;
  __syncthreads();
  for (int o = 1; o < SB; o <<= 1) {
    int t = (tid >= o) ? tsum[tid - o] : 0;
    __syncthreads();
    tsum[tid] += t;
    __syncthreads();
  }
  int run = tsum[tid] - s;
#pragma unroll
  for (int i = 0; i < SI; i++) {
    int idx = base + tid * SI + i;
    if (idx < n) off[idx] = run;
    run += v[i];
  }
  if (tid == SB - 1) bsum[blockIdx.x] = tsum[tid];
}

__global__ void scan2_kernel(int* bsum, int nb) {
  if (threadIdx.x == 0 && blockIdx.x == 0) {
    int run = 0;
    for (int b = 0; b < nb; b++) { int t = bsum[b]; bsum[b] = run; run += t; }
  }
}

__global__ void scan3_kernel(int* __restrict__ off, const int* __restrict__ bsum,
                             int n, int total) {
  int i = blockIdx.x * blockDim.x + threadIdx.x;
  if (i < n) off[i] += bsum[i / SCHUNK];
  if (i == 0) off[n] = total;
}

__global__ void fill_kernel(const int* __restrict__ src, const int* __restrict__ dst,
                            const int* __restrict__ off, int* __restrict__ cursor,
                            int* __restrict__ esrc, float* __restrict__ enorm,
                            const float* __restrict__ dis, int E) {
  int e = blockIdx.x * blockDim.x + threadIdx.x;
  if (e >= E) return;
  int s = src[e], d = dst[e];
  int p = off[d] + atomicAdd(&cursor[d], 1);
  esrc[p] = s;
  enorm[p] = dis[s] * dis[d];
}

// ---------------- W -> bf16 hi/lo, pre-arranged in MFMA B-fragment order ----
// Wf flat index: ((((ct*4 + kc)*2 + p)*64) + lane)*8 + j
//   value = split_p( W[k][col] ), k = kc*32 + (lane>>4)*8 + j, col = ct*16 + (lane&15)

__global__ void wconv_kernel(const float* __restrict__ W, ushort* __restrict__ Wf) {
  int idx = blockIdx.x * 256 + threadIdx.x;  // 0..32767
  int j = idx & 7;
  int l = (idx >> 3) & 63;
  int f = idx >> 9;
  int p = f & 1, kc = (f >> 1) & 3, ct = f >> 3;
  int k = kc * 32 + (l >> 4) * 8 + j;
  int col = ct * 16 + (l & 15);
  float w = W[k * D + col];
  ushort hi = bf16rne(w);
  ushort outv = hi;
  if (p) {
    float hf = __uint_as_float((uint32)hi << 16);
    outv = bf16rne(w - hf);
  }
  Wf[idx] = outv;
}

// ---------------- MFMA GEMM: C[N x 128] = A[N x 128] @ W[128 x 128] --------

__global__ __launch_bounds__(256) void gemm_kernel(const float* __restrict__ A,
                                                   const ushort* __restrict__ Wf,
                                                   float* __restrict__ C, int N) {
  __shared__ ushort As[128 * 128];  // bf16 tile, XOR-swizzled rows (32 KB)
  char* lds = (char*)As;
  int tid = threadIdx.x;
  int row0 = blockIdx.x * 128;

  // stage A: fp32 -> bf16 RNE, 4 elems/thread/iter, coalesced float4 loads
#pragma unroll
  for (int i = 0; i < 16; i++) {
    int f = i * 1024 + tid * 4;
    int r = f >> 7, c = f & 127;
    float4 v = make_float4(0.f, 0.f, 0.f, 0.f);
    if (row0 + r < N) v = *(const float4*)&A[(size_t)(row0 + r) * D + c];
    uint2 hv;
    hv.x = (uint32)bf16rne(v.x) | ((uint32)bf16rne(v.y) << 16);
    hv.y = (uint32)bf16rne(v.z) | ((uint32)bf16rne(v.w) << 16);
    int boff = (r * 256 + c * 2) ^ ((r & 7) << 4);
    *(uint2*)(lds + boff) = hv;
  }
  __syncthreads();

  int lane = tid & 63;
  int wv = tid >> 6;  // wave 0..3 -> rows wv*32 .. wv*32+31
  int m0 = wv * 32;
  int lr = lane & 15, lg = lane >> 4;

  // A fragments: lane holds A[row = m0+mt*16+lr][k = kc*32 + lg*8 + j]
  bf16x8 af[2][4];
#pragma unroll
  for (int mt = 0; mt < 2; mt++)
#pragma unroll
    for (int kc = 0; kc < 4; kc++) {
      int row = m0 + mt * 16 + lr;
      int boff = (row * 256 + kc * 64 + lg * 16) ^ ((row & 7) << 4);
      af[mt][kc] = *(bf16x8*)(lds + boff);
    }

  f32x4 acc[2][8];
#pragma unroll
  for (int mt = 0; mt < 2; mt++)
#pragma unroll
    for (int ct = 0; ct < 8; ct++) acc[mt][ct] = (f32x4){0.f, 0.f, 0.f, 0.f};

#pragma unroll 1
  for (int ct = 0; ct < 8; ct++) {
    bf16x8 bf_[4][2];
#pragma unroll
    for (int kc = 0; kc < 4; kc++)
#pragma unroll
      for (int p = 0; p < 2; p++)
        bf_[kc][p] = *(const bf16x8*)&Wf[(size_t)((((ct * 4 + kc) * 2 + p) * 64 + lane) * 8)];
#pragma unroll
    for (int kc = 0; kc < 4; kc++)
#pragma unroll
      for (int mt = 0; mt < 2; mt++) {
        acc[mt][ct] = __builtin_amdgcn_mfma_f32_16x16x32_bf16(af[mt][kc], bf_[kc][0], acc[mt][ct], 0, 0, 0);
        acc[mt][ct] = __builtin_amdgcn_mfma_f32_16x16x32_bf16(af[mt][kc], bf_[kc][1], acc[mt][ct], 0, 0, 0);
      }
  }

  // C/D layout: col = lane&15, row = (lane>>4)*4 + reg
#pragma unroll
  for (int mt = 0; mt < 2; mt++)
#pragma unroll
    for (int ct = 0; ct < 8; ct++)
#pragma unroll
      for (int r = 0; r < 4; r++) {
        int g = row0 + m0 + mt * 16 + lg * 4 + r;
        if (g < N) C[(size_t)g * D + ct * 16 + lr] = acc[mt][ct][r];
      }
}

// ---------------- aggregation: one wave per node, gather CSR in-edges -------

__global__ __launch_bounds__(256) void agg_kernel(const float* __restrict__ h,
                                                  const float* __restrict__ dis,
                                                  const int* __restrict__ off,
                                                  const int* __restrict__ esrc,
                                                  const float* __restrict__ enorm,
                                                  const float* __restrict__ bias,
                                                  float* __restrict__ out, int N, int doRelu) {
  int node = blockIdx.x * 4 + (threadIdx.x >> 6);
  if (node >= N) return;
  int lane = threadIdx.x & 63;
  int j0 = off[node], j1 = off[node + 1];
  float2 acc = make_float2(0.f, 0.f);
  for (int j = j0; j < j1; j++) {
    int s = esrc[j];
    float wgt = enorm[j];
    float2 hv = *(const float2*)&h[(size_t)s * D + lane * 2];
    acc.x += hv.x * wgt;
    acc.y += hv.y * wgt;
  }
  float ds = dis[node];
  float sw = ds * ds;
  float2 hv = *(const float2*)&h[(size_t)node * D + lane * 2];
  acc.x += hv.x * sw;
  acc.y += hv.y * sw;
  acc.x += bias[lane * 2];
  acc.y += bias[lane * 2 + 1];
  if (doRelu) { acc.x = fmaxf(acc.x, 0.f); acc.y = fmaxf(acc.y, 0.f); }
  *(float2*)&out[(size_t)node * D + lane * 2] = acc;
}

// ---------------- launch ----------------

extern "C" void kernel_launch(void* const* d_in, const int* in_sizes, int n_in,
                              void* d_out, int out_size, void* d_ws, size_t ws_size,
                              hipStream_t stream) {
  const float* x  = (const float*)d_in[0];
  const int*   ei = (const int*)d_in[1];
  const float* W1 = (const float*)d_in[2];
  const float* b1 = (const float*)d_in[3];
  const float* W2 = (const float*)d_in[4];
  const float* b2 = (const float*)d_in[5];
  const float* W3 = (const float*)d_in[6];
  const float* b3 = (const float*)d_in[7];
  int N = in_sizes[0] / D;
  int E = in_sizes[1] / 2;
  const int* srcp = ei;
  const int* dstp = ei + E;

  char* wp = (char*)d_ws;
  auto carve = [&](size_t bytes) {
    void* p = (void*)wp;
    wp += (bytes + 255) & ~(size_t)255;
    return p;
  };
  int*    cnt    = (int*)carve((size_t)N * 4);
  int*    cursor = (int*)carve((size_t)N * 4);
  int*    off    = (int*)carve((size_t)(N + 1) * 4);
  int*    bsum   = (int*)carve(256 * 4);
  float*  dis    = (float*)carve((size_t)N * 4);
  int*    esrc   = (int*)carve((size_t)E * 4);
  float*  enorm  = (float*)carve((size_t)E * 4);
  float*  h      = (float*)carve((size_t)N * D * 4);
  ushort* wf1    = (ushort*)carve(32768 * 2);
  ushort* wf2    = (ushort*)carve(32768 * 2);
  ushort* wf3    = (ushort*)carve(32768 * 2);

  hipMemsetAsync(cnt, 0, (size_t)N * 4, stream);
  hipMemsetAsync(cursor, 0, (size_t)N * 4, stream);

  const int tb = 256;
  wconv_kernel<<<128, 256, 0, stream>>>(W1, wf1);
  wconv_kernel<<<128, 256, 0, stream>>>(W2, wf2);
  wconv_kernel<<<128, 256, 0, stream>>>(W3, wf3);

  count_kernel<<<(E + tb - 1) / tb, tb, 0, stream>>>(dstp, cnt, E);
  dis_kernel<<<(N + tb - 1) / tb, tb, 0, stream>>>(cnt, dis, N);
  int nb = (N + SCHUNK - 1) / SCHUNK;
  scan1_kernel<<<nb, SB, 0, stream>>>(cnt, off, bsum, N);
  scan2_kernel<<<1, 64, 0, stream>>>(bsum, nb);
  scan3_kernel<<<(N + tb - 1) / tb, tb, 0, stream>>>(off, bsum, N, E);
  fill_kernel<<<(E + tb - 1) / tb, tb, 0, stream>>>(srcp, dstp, off, cursor, esrc, enorm, dis, E);

  int gb = (N + 127) / 128;
  float* out = (float*)d_out;
  gemm_kernel<<<gb, 256, 0, stream>>>(x, wf1, h, N);
  agg_kernel<<<(N + 3) / 4, 256, 0, stream>>>(h, dis, off, esrc, enorm, b1, out, N, 1);
  gemm_kernel<<<gb, 256, 0, stream>>>(out, wf2, h, N);
  agg_kernel<<<(N + 3) / 4, 256, 0, stream>>>(h, dis, off, esrc, enorm, b2, out, N, 1);
  gemm_kernel<<<gb, 256, 0, stream>>>(out, wf3, h, N);
  agg_kernel<<<(N + 3) / 4, 256, 0, stream>>>(h, dis, off, esrc, enorm, b3, out, N, 0);
}

// Round 3
// 430.032 us; speedup vs baseline: 2.0886x; 1.2375x over previous
//
#include <hip/hip_runtime.h>

#define D 128
#define SB 256
#define SI 8
#define SCHUNK (SB * SI)

typedef __attribute__((ext_vector_type(8))) short bf16x8;
typedef __attribute__((ext_vector_type(4))) float f32x4;
typedef unsigned int uint32;
typedef unsigned short ushort;

__device__ __forceinline__ ushort bf16rne(float f) {
  uint32 u = __float_as_uint(f);
  uint32 r = u + 0x7FFFu + ((u >> 16) & 1u);
  return (ushort)(r >> 16);
}
__device__ __forceinline__ float bf2f_lo(uint32 h) { return __uint_as_float(h << 16); }
__device__ __forceinline__ float bf2f_hi(uint32 h) { return __uint_as_float(h & 0xFFFF0000u); }
__device__ __forceinline__ uint32 packbf2(float x, float y) {
  return (uint32)bf16rne(x) | ((uint32)bf16rne(y) << 16);
}

// ---------------- degree / CSR build ----------------

__global__ void count_kernel(const int* __restrict__ dst, int* __restrict__ cnt, int E) {
  int e = blockIdx.x * blockDim.x + threadIdx.x;
  if (e < E) atomicAdd(&cnt[dst[e]], 1);
}

__global__ void dis_kernel(const int* __restrict__ cnt, float* __restrict__ dis, int N) {
  int i = blockIdx.x * blockDim.x + threadIdx.x;
  if (i < N) dis[i] = rsqrtf((float)(cnt[i] + 1));  // +1 self-loop
}

__global__ void scan1_kernel(const int* __restrict__ cnt, int* __restrict__ off,
                             int* __restrict__ bsum, int n) {
  __shared__ int tsum[SB];
  int tid = threadIdx.x;
  int base = blockIdx.x * SCHUNK;
  int v[SI];
  int s = 0;
#pragma unroll
  for (int i = 0; i < SI; i++) {
    int idx = base + tid * SI + i;
    v[i] = (idx < n) ? cnt[idx] : 0;
    s += v[i];
  }
  tsum[tid] = s;
  __syncthreads();
  for (int o = 1; o < SB; o <<= 1) {
    int t = (tid >= o) ? tsum[tid - o] : 0;
    __syncthreads();
    tsum[tid] += t;
    __syncthreads();
  }
  int run = tsum[tid] - s;
#pragma unroll
  for (int i = 0; i < SI; i++) {
    int idx = base + tid * SI + i;
    if (idx < n) off[idx] = run;
    run += v[i];
  }
  if (tid == SB - 1) bsum[blockIdx.x] = tsum[tid];
}

__global__ void scan2_kernel(int* bsum, int nb) {
  if (threadIdx.x == 0 && blockIdx.x == 0) {
    int run = 0;
    for (int b = 0; b < nb; b++) { int t = bsum[b]; bsum[b] = run; run += t; }
  }
}

__global__ void scan3_kernel(int* __restrict__ off, const int* __restrict__ bsum,
                             int n, int total) {
  int i = blockIdx.x * blockDim.x + threadIdx.x;
  if (i < n) off[i] += bsum[i / SCHUNK];
  if (i == 0) off[n] = total;
}

__global__ void fill_kernel(const int* __restrict__ src, const int* __restrict__ dst,
                            const int* __restrict__ off, int* __restrict__ cursor,
                            int* __restrict__ esrc, float* __restrict__ enorm,
                            const float* __restrict__ dis, int E) {
  int e = blockIdx.x * blockDim.x + threadIdx.x;
  if (e >= E) return;
  int s = src[e], d = dst[e];
  int p = off[d] + atomicAdd(&cursor[d], 1);
  esrc[p] = s;
  enorm[p] = dis[s] * dis[d];
}

// ---------------- W -> bf16 hi/lo in MFMA B-fragment order ----------------

__global__ void wconv_kernel(const float* __restrict__ W, ushort* __restrict__ Wf) {
  int idx = blockIdx.x * 256 + threadIdx.x;  // 0..32767
  int j = idx & 7;
  int l = (idx >> 3) & 63;
  int f = idx >> 9;
  int p = f & 1, kc = (f >> 1) & 3, ct = f >> 3;
  int k = kc * 32 + (l >> 4) * 8 + j;
  int col = ct * 16 + (l & 15);
  float w = W[k * D + col];
  ushort hi = bf16rne(w);
  ushort outv = hi;
  if (p) {
    float hf = __uint_as_float((uint32)hi << 16);
    outv = bf16rne(w - hf);
  }
  Wf[idx] = outv;
}

// ------------- shared MFMA core: LDS bf16 tile [128x128] -> Cb (bf16) -------

__device__ __forceinline__ void mfma_tile_store(char* lds, const ushort* __restrict__ Wf,
                                                ushort* __restrict__ Cb, int row0, int N,
                                                int tid) {
  int lane = tid & 63;
  int wv = tid >> 6;
  int m0 = wv * 32;
  int lr = lane & 15, lg = lane >> 4;

  bf16x8 af[2][4];
#pragma unroll
  for (int mt = 0; mt < 2; mt++)
#pragma unroll
    for (int kc = 0; kc < 4; kc++) {
      int row = m0 + mt * 16 + lr;
      int boff = (row * 256 + kc * 64 + lg * 16) ^ ((row & 7) << 4);
      af[mt][kc] = *(bf16x8*)(lds + boff);
    }

  f32x4 acc[2][8];
#pragma unroll
  for (int mt = 0; mt < 2; mt++)
#pragma unroll
    for (int ct = 0; ct < 8; ct++) acc[mt][ct] = (f32x4){0.f, 0.f, 0.f, 0.f};

#pragma unroll 1
  for (int ct = 0; ct < 8; ct++) {
    bf16x8 bf_[4][2];
#pragma unroll
    for (int kc = 0; kc < 4; kc++)
#pragma unroll
      for (int p = 0; p < 2; p++)
        bf_[kc][p] = *(const bf16x8*)&Wf[(size_t)((((ct * 4 + kc) * 2 + p) * 64 + lane) * 8)];
#pragma unroll
    for (int kc = 0; kc < 4; kc++)
#pragma unroll
      for (int mt = 0; mt < 2; mt++) {
        acc[mt][ct] = __builtin_amdgcn_mfma_f32_16x16x32_bf16(af[mt][kc], bf_[kc][0], acc[mt][ct], 0, 0, 0);
        acc[mt][ct] = __builtin_amdgcn_mfma_f32_16x16x32_bf16(af[mt][kc], bf_[kc][1], acc[mt][ct], 0, 0, 0);
      }
  }

  __syncthreads();  // done reading A-tile; reuse LDS for epilogue

  // scatter acc into LDS as bf16 (C/D layout: col=lane&15, row=(lane>>4)*4+r)
#pragma unroll
  for (int mt = 0; mt < 2; mt++)
#pragma unroll
    for (int ct = 0; ct < 8; ct++)
#pragma unroll
      for (int r = 0; r < 4; r++) {
        int row = m0 + mt * 16 + lg * 4 + r;
        int col = ct * 16 + lr;
        int boff = (row * 256 + col * 2) ^ ((row & 7) << 4);
        *(ushort*)(lds + boff) = bf16rne(acc[mt][ct][r]);
      }
  __syncthreads();

  // coalesced bf16 store: 16B per lane, contiguous
#pragma unroll
  for (int i = 0; i < 8; i++) {
    int f = i * 4096 + tid * 16;  // byte offset in 32KB tile
    int row = f >> 8;
    int boff = f ^ ((row & 7) << 4);
    if (row0 + row < N) {
      uint4 v = *(uint4*)(lds + boff);
      *(uint4*)((char*)Cb + (size_t)(row0 + row) * 256 + (f & 255)) = v;
    }
  }
}

// ---------------- GEMM1: t1[N x 128](bf16) = x(fp32) @ W1 ------------------

__global__ __launch_bounds__(256) void gemm1_kernel(const float* __restrict__ A,
                                                    const ushort* __restrict__ Wf,
                                                    ushort* __restrict__ Cb, int N) {
  __shared__ ushort As[128 * 128];
  char* lds = (char*)As;
  int tid = threadIdx.x;
  int row0 = blockIdx.x * 128;
#pragma unroll
  for (int i = 0; i < 16; i++) {
    int f = i * 1024 + tid * 4;
    int r = f >> 7, c = f & 127;
    float4 v = make_float4(0.f, 0.f, 0.f, 0.f);
    if (row0 + r < N) v = *(const float4*)&A[(size_t)(row0 + r) * D + c];
    uint2 hv;
    hv.x = packbf2(v.x, v.y);
    hv.y = packbf2(v.z, v.w);
    int boff = (r * 256 + c * 2) ^ ((r & 7) << 4);
    *(uint2*)(lds + boff) = hv;
  }
  __syncthreads();
  mfma_tile_store(lds, Wf, Cb, row0, N, tid);
}

// ------- fused: t'[N x128](bf16) = relu(Agg(t)+bias) @ W  ------------------

__global__ __launch_bounds__(256) void fused_kernel(const ushort* __restrict__ t,
                                                    const float* __restrict__ dis,
                                                    const int* __restrict__ off,
                                                    const int* __restrict__ esrc,
                                                    const float* __restrict__ enorm,
                                                    const float* __restrict__ bias,
                                                    const ushort* __restrict__ Wf,
                                                    ushort* __restrict__ Cb, int N) {
  __shared__ ushort As[128 * 128];
  char* lds = (char*)As;
  int tid = threadIdx.x;
  int row0 = blockIdx.x * 128;
  int lane = tid & 63, wv = tid >> 6;
  float bx = bias[lane * 2], by = bias[lane * 2 + 1];

  for (int n = 0; n < 32; n++) {
    int r = wv * 32 + n;
    int node = row0 + r;
    float ax = 0.f, ay = 0.f;
    if (node < N) {
      int j0 = off[node], j1 = off[node + 1];
      int j = j0;
      for (; j + 3 < j1; j += 4) {
        int s0 = esrc[j], s1 = esrc[j + 1], s2 = esrc[j + 2], s3 = esrc[j + 3];
        float w0 = enorm[j], w1 = enorm[j + 1], w2 = enorm[j + 2], w3 = enorm[j + 3];
        uint32 h0 = *(const uint32*)(t + (size_t)s0 * D + lane * 2);
        uint32 h1 = *(const uint32*)(t + (size_t)s1 * D + lane * 2);
        uint32 h2 = *(const uint32*)(t + (size_t)s2 * D + lane * 2);
        uint32 h3 = *(const uint32*)(t + (size_t)s3 * D + lane * 2);
        ax += w0 * bf2f_lo(h0) + w1 * bf2f_lo(h1) + w2 * bf2f_lo(h2) + w3 * bf2f_lo(h3);
        ay += w0 * bf2f_hi(h0) + w1 * bf2f_hi(h1) + w2 * bf2f_hi(h2) + w3 * bf2f_hi(h3);
      }
      for (; j < j1; j++) {
        int s = esrc[j];
        float w = enorm[j];
        uint32 h = *(const uint32*)(t + (size_t)s * D + lane * 2);
        ax += w * bf2f_lo(h);
        ay += w * bf2f_hi(h);
      }
      float dsv = dis[node];
      float sw = dsv * dsv;
      uint32 h = *(const uint32*)(t + (size_t)node * D + lane * 2);
      ax += sw * bf2f_lo(h) + bx;
      ay += sw * bf2f_hi(h) + by;
      ax = fmaxf(ax, 0.f);
      ay = fmaxf(ay, 0.f);
    }
    int boff = (r * 256 + lane * 4) ^ ((r & 7) << 4);
    *(uint32*)(lds + boff) = packbf2(ax, ay);
  }
  __syncthreads();
  mfma_tile_store(lds, Wf, Cb, row0, N, tid);
}

// ---------------- final aggregation: fp32 out = Agg(t3) + b3 ---------------

__global__ __launch_bounds__(256) void agg3_kernel(const ushort* __restrict__ t,
                                                   const float* __restrict__ dis,
                                                   const int* __restrict__ off,
                                                   const int* __restrict__ esrc,
                                                   const float* __restrict__ enorm,
                                                   const float* __restrict__ bias,
                                                   float* __restrict__ out, int N) {
  int node = blockIdx.x * 4 + (threadIdx.x >> 6);
  if (node >= N) return;
  int lane = threadIdx.x & 63;
  int j0 = off[node], j1 = off[node + 1];
  float ax = 0.f, ay = 0.f;
  int j = j0;
  for (; j + 3 < j1; j += 4) {
    int s0 = esrc[j], s1 = esrc[j + 1], s2 = esrc[j + 2], s3 = esrc[j + 3];
    float w0 = enorm[j], w1 = enorm[j + 1], w2 = enorm[j + 2], w3 = enorm[j + 3];
    uint32 h0 = *(const uint32*)(t + (size_t)s0 * D + lane * 2);
    uint32 h1 = *(const uint32*)(t + (size_t)s1 * D + lane * 2);
    uint32 h2 = *(const uint32*)(t + (size_t)s2 * D + lane * 2);
    uint32 h3 = *(const uint32*)(t + (size_t)s3 * D + lane * 2);
    ax += w0 * bf2f_lo(h0) + w1 * bf2f_lo(h1) + w2 * bf2f_lo(h2) + w3 * bf2f_lo(h3);
    ay += w0 * bf2f_hi(h0) + w1 * bf2f_hi(h1) + w2 * bf2f_hi(h2) + w3 * bf2f_hi(h3);
  }
  for (; j < j1; j++) {
    int s = esrc[j];
    float w = enorm[j];
    uint32 h = *(const uint32*)(t + (size_t)s * D + lane * 2);
    ax += w * bf2f_lo(h);
    ay += w * bf2f_hi(h);
  }
  float dsv = dis[node];
  float sw = dsv * dsv;
  uint32 h = *(const uint32*)(t + (size_t)node * D + lane * 2);
  ax += sw * bf2f_lo(h) + bias[lane * 2];
  ay += sw * bf2f_hi(h) + bias[lane * 2 + 1];
  *(float2*)&out[(size_t)node * D + lane * 2] = make_float2(ax, ay);
}

// ---------------- launch ----------------

extern "C" void kernel_launch(void* const* d_in, const int* in_sizes, int n_in,
                              void* d_out, int out_size, void* d_ws, size_t ws_size,
                              hipStream_t stream) {
  const float* x  = (const float*)d_in[0];
  const int*   ei = (const int*)d_in[1];
  const float* W1 = (const float*)d_in[2];
  const float* b1 = (const float*)d_in[3];
  const float* W2 = (const float*)d_in[4];
  const float* b2 = (const float*)d_in[5];
  const float* W3 = (const float*)d_in[6];
  const float* b3 = (const float*)d_in[7];
  int N = in_sizes[0] / D;
  int E = in_sizes[1] / 2;
  const int* srcp = ei;
  const int* dstp = ei + E;

  char* wp = (char*)d_ws;
  auto carve = [&](size_t bytes) {
    void* p = (void*)wp;
    wp += (bytes + 255) & ~(size_t)255;
    return p;
  };
  int*    cnt    = (int*)carve((size_t)N * 4);
  int*    cursor = (int*)carve((size_t)N * 4);
  int*    off    = (int*)carve((size_t)(N + 1) * 4);
  int*    bsum   = (int*)carve(256 * 4);
  float*  dis    = (float*)carve((size_t)N * 4);
  int*    esrc   = (int*)carve((size_t)E * 4);
  float*  enorm  = (float*)carve((size_t)E * 4);
  ushort* t1     = (ushort*)carve((size_t)N * D * 2);  // also reused as t3
  ushort* t2     = (ushort*)carve((size_t)N * D * 2);
  ushort* wf1    = (ushort*)carve(32768 * 2);
  ushort* wf2    = (ushort*)carve(32768 * 2);
  ushort* wf3    = (ushort*)carve(32768 * 2);

  hipMemsetAsync(cnt, 0, (size_t)N * 4, stream);
  hipMemsetAsync(cursor, 0, (size_t)N * 4, stream);

  const int tb = 256;
  wconv_kernel<<<128, 256, 0, stream>>>(W1, wf1);
  wconv_kernel<<<128, 256, 0, stream>>>(W2, wf2);
  wconv_kernel<<<128, 256, 0, stream>>>(W3, wf3);

  count_kernel<<<(E + tb - 1) / tb, tb, 0, stream>>>(dstp, cnt, E);
  dis_kernel<<<(N + tb - 1) / tb, tb, 0, stream>>>(cnt, dis, N);
  int nb = (N + SCHUNK - 1) / SCHUNK;
  scan1_kernel<<<nb, SB, 0, stream>>>(cnt, off, bsum, N);
  scan2_kernel<<<1, 64, 0, stream>>>(bsum, nb);
  scan3_kernel<<<(N + tb - 1) / tb, tb, 0, stream>>>(off, bsum, N, E);
  fill_kernel<<<(E + tb - 1) / tb, tb, 0, stream>>>(srcp, dstp, off, cursor, esrc, enorm, dis, E);

  int gb = (N + 127) / 128;
  float* out = (float*)d_out;
  ushort* t3 = t1;  // t1 dead once t2 is built
  gemm1_kernel<<<gb, 256, 0, stream>>>(x, wf1, t1, N);
  fused_kernel<<<gb, 256, 0, stream>>>(t1, dis, off, esrc, enorm, b1, wf2, t2, N);
  fused_kernel<<<gb, 256, 0, stream>>>(t2, dis, off, esrc, enorm, b2, wf3, t3, N);
  agg3_kernel<<<(N + 3) / 4, 256, 0, stream>>>(t3, dis, off, esrc, enorm, b3, out, N);
}

// Round 4
// 290.405 us; speedup vs baseline: 3.0928x; 1.4808x over previous
//
#include <hip/hip_runtime.h>

#define D 128
#define SB 256
#define SI 8
#define SCHUNK (SB * SI)

typedef __attribute__((ext_vector_type(8))) short bf16x8;
typedef __attribute__((ext_vector_type(4))) float f32x4;
typedef unsigned int uint32;
typedef unsigned short ushort;

__device__ __forceinline__ ushort bf16rne(float f) {
  uint32 u = __float_as_uint(f);
  uint32 r = u + 0x7FFFu + ((u >> 16) & 1u);
  return (ushort)(r >> 16);
}
__device__ __forceinline__ float bf2f_lo(uint32 h) { return __uint_as_float(h << 16); }
__device__ __forceinline__ float bf2f_hi(uint32 h) { return __uint_as_float(h & 0xFFFF0000u); }
__device__ __forceinline__ uint32 packbf2(float x, float y) {
  return (uint32)bf16rne(x) | ((uint32)bf16rne(y) << 16);
}

// ---------------- degree / CSR build ----------------

__global__ void count_kernel(const int* __restrict__ dst, int* __restrict__ cnt, int E) {
  int e = blockIdx.x * blockDim.x + threadIdx.x;
  if (e < E) atomicAdd(&cnt[dst[e]], 1);
}

__global__ void dis_kernel(const int* __restrict__ cnt, float* __restrict__ dis, int N) {
  int i = blockIdx.x * blockDim.x + threadIdx.x;
  if (i < N) dis[i] = rsqrtf((float)(cnt[i] + 1));  // +1 self-loop
}

__global__ void scan1_kernel(const int* __restrict__ cnt, int* __restrict__ off,
                             int* __restrict__ bsum, int n) {
  __shared__ int tsum[SB];
  int tid = threadIdx.x;
  int base = blockIdx.x * SCHUNK;
  int v[SI];
  int s = 0;
#pragma unroll
  for (int i = 0; i < SI; i++) {
    int idx = base + tid * SI + i;
    v[i] = (idx < n) ? cnt[idx] : 0;
    s += v[i];
  }
  tsum[tid] = s;
  __syncthreads();
  for (int o = 1; o < SB; o <<= 1) {
    int t = (tid >= o) ? tsum[tid - o] : 0;
    __syncthreads();
    tsum[tid] += t;
    __syncthreads();
  }
  int run = tsum[tid] - s;
#pragma unroll
  for (int i = 0; i < SI; i++) {
    int idx = base + tid * SI + i;
    if (idx < n) off[idx] = run;
    run += v[i];
  }
  if (tid == SB - 1) bsum[blockIdx.x] = tsum[tid];
}

__global__ void scan2_kernel(int* bsum, int nb) {
  if (threadIdx.x == 0 && blockIdx.x == 0) {
    int run = 0;
    for (int b = 0; b < nb; b++) { int t = bsum[b]; bsum[b] = run; run += t; }
  }
}

__global__ void scan3_kernel(int* __restrict__ off, const int* __restrict__ bsum,
                             int n, int total) {
  int i = blockIdx.x * blockDim.x + threadIdx.x;
  if (i < n) off[i] += bsum[i / SCHUNK];
  if (i == 0) off[n] = total;
}

__global__ void fill_kernel(const int* __restrict__ src, const int* __restrict__ dst,
                            const int* __restrict__ off, int* __restrict__ cursor,
                            int* __restrict__ esrc, float* __restrict__ enorm,
                            const float* __restrict__ dis, int E) {
  int e = blockIdx.x * blockDim.x + threadIdx.x;
  if (e >= E) return;
  int s = src[e], d = dst[e];
  int p = off[d] + atomicAdd(&cursor[d], 1);
  esrc[p] = s;
  enorm[p] = dis[s] * dis[d];
}

// ---------------- W -> bf16 hi/lo in MFMA B-fragment order ----------------

__global__ void wconv_kernel(const float* __restrict__ W, ushort* __restrict__ Wf) {
  int idx = blockIdx.x * 256 + threadIdx.x;  // 0..32767
  int j = idx & 7;
  int l = (idx >> 3) & 63;
  int f = idx >> 9;
  int p = f & 1, kc = (f >> 1) & 3, ct = f >> 3;
  int k = kc * 32 + (l >> 4) * 8 + j;
  int col = ct * 16 + (l & 15);
  float w = W[k * D + col];
  ushort hi = bf16rne(w);
  ushort outv = hi;
  if (p) {
    float hf = __uint_as_float((uint32)hi << 16);
    outv = bf16rne(w - hf);
  }
  Wf[idx] = outv;
}

// ------------- MFMA core, M=128 tile (used by gemm1) ----------------------

__device__ __forceinline__ void mfma_tile_store(char* lds, const ushort* __restrict__ Wf,
                                                ushort* __restrict__ Cb, int row0, int N,
                                                int tid) {
  int lane = tid & 63;
  int wv = tid >> 6;
  int m0 = wv * 32;
  int lr = lane & 15, lg = lane >> 4;

  bf16x8 af[2][4];
#pragma unroll
  for (int mt = 0; mt < 2; mt++)
#pragma unroll
    for (int kc = 0; kc < 4; kc++) {
      int row = m0 + mt * 16 + lr;
      int boff = (row * 256 + kc * 64 + lg * 16) ^ ((row & 7) << 4);
      af[mt][kc] = *(bf16x8*)(lds + boff);
    }

  f32x4 acc[2][8];
#pragma unroll
  for (int mt = 0; mt < 2; mt++)
#pragma unroll
    for (int ct = 0; ct < 8; ct++) acc[mt][ct] = (f32x4){0.f, 0.f, 0.f, 0.f};

#pragma unroll 1
  for (int ct = 0; ct < 8; ct++) {
    bf16x8 bf_[4][2];
#pragma unroll
    for (int kc = 0; kc < 4; kc++)
#pragma unroll
      for (int p = 0; p < 2; p++)
        bf_[kc][p] = *(const bf16x8*)&Wf[(size_t)((((ct * 4 + kc) * 2 + p) * 64 + lane) * 8)];
#pragma unroll
    for (int kc = 0; kc < 4; kc++)
#pragma unroll
      for (int mt = 0; mt < 2; mt++) {
        acc[mt][ct] = __builtin_amdgcn_mfma_f32_16x16x32_bf16(af[mt][kc], bf_[kc][0], acc[mt][ct], 0, 0, 0);
        acc[mt][ct] = __builtin_amdgcn_mfma_f32_16x16x32_bf16(af[mt][kc], bf_[kc][1], acc[mt][ct], 0, 0, 0);
      }
  }

  __syncthreads();

#pragma unroll
  for (int mt = 0; mt < 2; mt++)
#pragma unroll
    for (int ct = 0; ct < 8; ct++)
#pragma unroll
      for (int r = 0; r < 4; r++) {
        int row = m0 + mt * 16 + lg * 4 + r;
        int col = ct * 16 + lr;
        int boff = (row * 256 + col * 2) ^ ((row & 7) << 4);
        *(ushort*)(lds + boff) = bf16rne(acc[mt][ct][r]);
      }
  __syncthreads();

#pragma unroll
  for (int i = 0; i < 8; i++) {
    int f = i * 4096 + tid * 16;
    int row = f >> 8;
    int boff = f ^ ((row & 7) << 4);
    if (row0 + row < N) {
      uint4 v = *(uint4*)(lds + boff);
      *(uint4*)((char*)Cb + (size_t)(row0 + row) * 256 + (f & 255)) = v;
    }
  }
}

// ------------- MFMA core, M=64 tile (used by fused) ------------------------

__device__ __forceinline__ void mfma64_store(char* lds, const ushort* __restrict__ Wf,
                                             ushort* __restrict__ Cb, int row0, int N,
                                             int tid) {
  int lane = tid & 63;
  int wv = tid >> 6;
  int m0 = wv * 16;
  int lr = lane & 15, lg = lane >> 4;

  bf16x8 af[4];
#pragma unroll
  for (int kc = 0; kc < 4; kc++) {
    int row = m0 + lr;
    int boff = (row * 256 + kc * 64 + lg * 16) ^ ((row & 7) << 4);
    af[kc] = *(bf16x8*)(lds + boff);
  }

  f32x4 acc[8];
#pragma unroll
  for (int ct = 0; ct < 8; ct++) acc[ct] = (f32x4){0.f, 0.f, 0.f, 0.f};

#pragma unroll 1
  for (int ct = 0; ct < 8; ct++) {
    bf16x8 bf_[4][2];
#pragma unroll
    for (int kc = 0; kc < 4; kc++)
#pragma unroll
      for (int p = 0; p < 2; p++)
        bf_[kc][p] = *(const bf16x8*)&Wf[(size_t)((((ct * 4 + kc) * 2 + p) * 64 + lane) * 8)];
#pragma unroll
    for (int kc = 0; kc < 4; kc++) {
      acc[ct] = __builtin_amdgcn_mfma_f32_16x16x32_bf16(af[kc], bf_[kc][0], acc[ct], 0, 0, 0);
      acc[ct] = __builtin_amdgcn_mfma_f32_16x16x32_bf16(af[kc], bf_[kc][1], acc[ct], 0, 0, 0);
    }
  }

  __syncthreads();

#pragma unroll
  for (int ct = 0; ct < 8; ct++)
#pragma unroll
    for (int r = 0; r < 4; r++) {
      int row = m0 + lg * 4 + r;
      int col = ct * 16 + lr;
      int boff = (row * 256 + col * 2) ^ ((row & 7) << 4);
      *(ushort*)(lds + boff) = bf16rne(acc[ct][r]);
    }
  __syncthreads();

#pragma unroll
  for (int i = 0; i < 4; i++) {
    int f = i * 4096 + tid * 16;
    int row = f >> 8;
    int boff = f ^ ((row & 7) << 4);
    if (row0 + row < N) {
      uint4 v = *(uint4*)(lds + boff);
      *(uint4*)((char*)Cb + (size_t)(row0 + row) * 256 + (f & 255)) = v;
    }
  }
}

// ---------------- GEMM1: t1[N x 128](bf16) = x(fp32) @ W1 ------------------

__global__ __launch_bounds__(256) void gemm1_kernel(const float* __restrict__ A,
                                                    const ushort* __restrict__ Wf,
                                                    ushort* __restrict__ Cb, int N) {
  __shared__ ushort As[128 * 128];
  char* lds = (char*)As;
  int tid = threadIdx.x;
  int row0 = blockIdx.x * 128;
#pragma unroll
  for (int i = 0; i < 16; i++) {
    int f = i * 1024 + tid * 4;
    int r = f >> 7, c = f & 127;
    float4 v = make_float4(0.f, 0.f, 0.f, 0.f);
    if (row0 + r < N) v = *(const float4*)&A[(size_t)(row0 + r) * D + c];
    uint2 hv;
    hv.x = packbf2(v.x, v.y);
    hv.y = packbf2(v.z, v.w);
    int boff = (r * 256 + c * 2) ^ ((r & 7) << 4);
    *(uint2*)(lds + boff) = hv;
  }
  __syncthreads();
  mfma_tile_store(lds, Wf, Cb, row0, N, tid);
}

// ------- fused: t'[N x128](bf16) = relu(Agg(t)+bias) @ W -------------------
// gather: 4 row-groups of 16 lanes per wave; each group loads full 256B rows

__global__ __launch_bounds__(256) void fused_kernel(const ushort* __restrict__ t,
                                                    const float* __restrict__ dis,
                                                    const int* __restrict__ off,
                                                    const int* __restrict__ esrc,
                                                    const float* __restrict__ enorm,
                                                    const float* __restrict__ bias,
                                                    const ushort* __restrict__ Wf,
                                                    ushort* __restrict__ Cb, int N) {
  __shared__ ushort As[64 * 128];
  char* lds = (char*)As;
  int tid = threadIdx.x;
  int row0 = blockIdx.x * 64;
  int lane = tid & 63, wv = tid >> 6;
  int q = lane & 15, g = lane >> 4;
  float4 b0 = *(const float4*)&bias[q * 8];
  float4 b1 = *(const float4*)&bias[q * 8 + 4];

#pragma unroll 1
  for (int n4 = 0; n4 < 4; n4++) {
    int r = wv * 16 + n4 * 4 + g;
    int node = row0 + r;
    float a[8];
#pragma unroll
    for (int i = 0; i < 8; i++) a[i] = 0.f;

    if (node < N) {
      int j0 = off[node], j1 = off[node + 1];
      float dsv = dis[node];
      float sw = dsv * dsv;
      int idx = j0;
      int sA = node; float wA = sw;
      if (idx < j1) { sA = esrc[idx]; wA = enorm[idx]; }
      while (idx <= j1) {
        uint4 hv = *(const uint4*)(t + (size_t)sA * D + q * 8);
        int nxt = idx + 1;
        int sB = node; float wB = sw;
        if (nxt < j1) { sB = esrc[nxt]; wB = enorm[nxt]; }
        a[0] += wA * bf2f_lo(hv.x); a[1] += wA * bf2f_hi(hv.x);
        a[2] += wA * bf2f_lo(hv.y); a[3] += wA * bf2f_hi(hv.y);
        a[4] += wA * bf2f_lo(hv.z); a[5] += wA * bf2f_hi(hv.z);
        a[6] += wA * bf2f_lo(hv.w); a[7] += wA * bf2f_hi(hv.w);
        sA = sB; wA = wB; idx = nxt;
      }
      a[0] = fmaxf(a[0] + b0.x, 0.f); a[1] = fmaxf(a[1] + b0.y, 0.f);
      a[2] = fmaxf(a[2] + b0.z, 0.f); a[3] = fmaxf(a[3] + b0.w, 0.f);
      a[4] = fmaxf(a[4] + b1.x, 0.f); a[5] = fmaxf(a[5] + b1.y, 0.f);
      a[6] = fmaxf(a[6] + b1.z, 0.f); a[7] = fmaxf(a[7] + b1.w, 0.f);
    }
    uint4 pv;
    pv.x = packbf2(a[0], a[1]);
    pv.y = packbf2(a[2], a[3]);
    pv.z = packbf2(a[4], a[5]);
    pv.w = packbf2(a[6], a[7]);
    int boff = (r * 256 + q * 16) ^ ((r & 7) << 4);
    *(uint4*)(lds + boff) = pv;
  }
  __syncthreads();
  mfma64_store(lds, Wf, Cb, row0, N, tid);
}

// ---------------- final aggregation: fp32 out = Agg(t3) + b3 ---------------

__global__ __launch_bounds__(256) void agg3_kernel(const ushort* __restrict__ t,
                                                   const float* __restrict__ dis,
                                                   const int* __restrict__ off,
                                                   const int* __restrict__ esrc,
                                                   const float* __restrict__ enorm,
                                                   const float* __restrict__ bias,
                                                   float* __restrict__ out, int N) {
  int tid = threadIdx.x;
  int lane = tid & 63, wv = tid >> 6;
  int q = lane & 15, g = lane >> 4;
  int node = blockIdx.x * 16 + wv * 4 + g;
  if (node >= N) return;
  float4 b0 = *(const float4*)&bias[q * 8];
  float4 b1 = *(const float4*)&bias[q * 8 + 4];

  float a[8];
#pragma unroll
  for (int i = 0; i < 8; i++) a[i] = 0.f;

  int j0 = off[node], j1 = off[node + 1];
  float dsv = dis[node];
  float sw = dsv * dsv;
  int idx = j0;
  int sA = node; float wA = sw;
  if (idx < j1) { sA = esrc[idx]; wA = enorm[idx]; }
  while (idx <= j1) {
    uint4 hv = *(const uint4*)(t + (size_t)sA * D + q * 8);
    int nxt = idx + 1;
    int sB = node; float wB = sw;
    if (nxt < j1) { sB = esrc[nxt]; wB = enorm[nxt]; }
    a[0] += wA * bf2f_lo(hv.x); a[1] += wA * bf2f_hi(hv.x);
    a[2] += wA * bf2f_lo(hv.y); a[3] += wA * bf2f_hi(hv.y);
    a[4] += wA * bf2f_lo(hv.z); a[5] += wA * bf2f_hi(hv.z);
    a[6] += wA * bf2f_lo(hv.w); a[7] += wA * bf2f_hi(hv.w);
    sA = sB; wA = wB; idx = nxt;
  }
  float4 o0 = make_float4(a[0] + b0.x, a[1] + b0.y, a[2] + b0.z, a[3] + b0.w);
  float4 o1 = make_float4(a[4] + b1.x, a[5] + b1.y, a[6] + b1.z, a[7] + b1.w);
  *(float4*)&out[(size_t)node * D + q * 8] = o0;
  *(float4*)&out[(size_t)node * D + q * 8 + 4] = o1;
}

// ---------------- launch ----------------

extern "C" void kernel_launch(void* const* d_in, const int* in_sizes, int n_in,
                              void* d_out, int out_size, void* d_ws, size_t ws_size,
                              hipStream_t stream) {
  const float* x  = (const float*)d_in[0];
  const int*   ei = (const int*)d_in[1];
  const float* W1 = (const float*)d_in[2];
  const float* b1 = (const float*)d_in[3];
  const float* W2 = (const float*)d_in[4];
  const float* b2 = (const float*)d_in[5];
  const float* W3 = (const float*)d_in[6];
  const float* b3 = (const float*)d_in[7];
  int N = in_sizes[0] / D;
  int E = in_sizes[1] / 2;
  const int* srcp = ei;
  const int* dstp = ei + E;

  char* wp = (char*)d_ws;
  auto carve = [&](size_t bytes) {
    void* p = (void*)wp;
    wp += (bytes + 255) & ~(size_t)255;
    return p;
  };
  int*    cnt    = (int*)carve((size_t)N * 4);
  int*    cursor = (int*)carve((size_t)N * 4);
  int*    off    = (int*)carve((size_t)(N + 1) * 4);
  int*    bsum   = (int*)carve(256 * 4);
  float*  dis    = (float*)carve((size_t)N * 4);
  int*    esrc   = (int*)carve((size_t)E * 4);
  float*  enorm  = (float*)carve((size_t)E * 4);
  ushort* t1     = (ushort*)carve((size_t)N * D * 2);  // reused as t3
  ushort* t2     = (ushort*)carve((size_t)N * D * 2);
  ushort* wf1    = (ushort*)carve(32768 * 2);
  ushort* wf2    = (ushort*)carve(32768 * 2);
  ushort* wf3    = (ushort*)carve(32768 * 2);

  hipMemsetAsync(cnt, 0, (size_t)N * 4, stream);
  hipMemsetAsync(cursor, 0, (size_t)N * 4, stream);

  const int tb = 256;
  wconv_kernel<<<128, 256, 0, stream>>>(W1, wf1);
  wconv_kernel<<<128, 256, 0, stream>>>(W2, wf2);
  wconv_kernel<<<128, 256, 0, stream>>>(W3, wf3);

  count_kernel<<<(E + tb - 1) / tb, tb, 0, stream>>>(dstp, cnt, E);
  dis_kernel<<<(N + tb - 1) / tb, tb, 0, stream>>>(cnt, dis, N);
  int nb = (N + SCHUNK - 1) / SCHUNK;
  scan1_kernel<<<nb, SB, 0, stream>>>(cnt, off, bsum, N);
  scan2_kernel<<<1, 64, 0, stream>>>(bsum, nb);
  scan3_kernel<<<(N + tb - 1) / tb, tb, 0, stream>>>(off, bsum, N, E);
  fill_kernel<<<(E + tb - 1) / tb, tb, 0, stream>>>(srcp, dstp, off, cursor, esrc, enorm, dis, E);

  float* out = (float*)d_out;
  ushort* t3 = t1;  // t1 dead once t2 is built
  gemm1_kernel<<<(N + 127) / 128, 256, 0, stream>>>(x, wf1, t1, N);
  int fb = (N + 63) / 64;
  fused_kernel<<<fb, 256, 0, stream>>>(t1, dis, off, esrc, enorm, b1, wf2, t2, N);
  fused_kernel<<<fb, 256, 0, stream>>>(t2, dis, off, esrc, enorm, b2, wf3, t3, N);
  agg3_kernel<<<(N + 15) / 16, 256, 0, stream>>>(t3, dis, off, esrc, enorm, b3, out, N);
}

// Round 5
// 263.259 us; speedup vs baseline: 3.4117x; 1.1031x over previous
//
#include <hip/hip_runtime.h>

#define D 128
#define SB 256
#define SI 8
#define SCHUNK (SB * SI)

typedef __attribute__((ext_vector_type(8))) short bf16x8;
typedef __attribute__((ext_vector_type(4))) float f32x4;
typedef unsigned int uint32;
typedef unsigned short ushort;

__device__ __forceinline__ ushort bf16rne(float f) {
  uint32 u = __float_as_uint(f);
  uint32 r = u + 0x7FFFu + ((u >> 16) & 1u);
  return (ushort)(r >> 16);
}
__device__ __forceinline__ float bf2f_lo(uint32 h) { return __uint_as_float(h << 16); }
__device__ __forceinline__ float bf2f_hi(uint32 h) { return __uint_as_float(h & 0xFFFF0000u); }
__device__ __forceinline__ uint32 packbf2(float x, float y) {
  return (uint32)bf16rne(x) | ((uint32)bf16rne(y) << 16);
}
__device__ __forceinline__ void acc8(float* a, float w, uint4 h) {
  a[0] += w * bf2f_lo(h.x); a[1] += w * bf2f_hi(h.x);
  a[2] += w * bf2f_lo(h.y); a[3] += w * bf2f_hi(h.y);
  a[4] += w * bf2f_lo(h.z); a[5] += w * bf2f_hi(h.z);
  a[6] += w * bf2f_lo(h.w); a[7] += w * bf2f_hi(h.w);
}

// ---------------- degree / CSR build ----------------

__global__ void count_kernel(const int* __restrict__ dst, int* __restrict__ cnt, int E) {
  int e = blockIdx.x * blockDim.x + threadIdx.x;
  if (e < E) atomicAdd(&cnt[dst[e]], 1);
}

// scan1 also produces dis = rsqrt(cnt+1)
__global__ void scan1_kernel(const int* __restrict__ cnt, int* __restrict__ off,
                             int* __restrict__ bsum, float* __restrict__ dis, int n) {
  __shared__ int tsum[SB];
  int tid = threadIdx.x;
  int base = blockIdx.x * SCHUNK;
  int v[SI];
  int s = 0;
#pragma unroll
  for (int i = 0; i < SI; i++) {
    int idx = base + tid * SI + i;
    v[i] = (idx < n) ? cnt[idx] : 0;
    s += v[i];
  }
  tsum[tid] = s;
  __syncthreads();
  for (int o = 1; o < SB; o <<= 1) {
    int t = (tid >= o) ? tsum[tid - o] : 0;
    __syncthreads();
    tsum[tid] += t;
    __syncthreads();
  }
  int run = tsum[tid] - s;
#pragma unroll
  for (int i = 0; i < SI; i++) {
    int idx = base + tid * SI + i;
    if (idx < n) {
      off[idx] = run;
      dis[idx] = rsqrtf((float)(v[i] + 1));
    }
    run += v[i];
  }
  if (tid == SB - 1) bsum[blockIdx.x] = tsum[tid];
}

__global__ void scan2_kernel(int* bsum, int nb) {
  if (threadIdx.x == 0 && blockIdx.x == 0) {
    int run = 0;
    for (int b = 0; b < nb; b++) { int t = bsum[b]; bsum[b] = run; run += t; }
  }
}

__global__ void scan3_kernel(int* __restrict__ off, const int* __restrict__ bsum,
                             int n, int total) {
  int i = blockIdx.x * blockDim.x + threadIdx.x;
  if (i < n) off[i] += bsum[i / SCHUNK];
  if (i == 0) off[n] = total;
}

// fill: uses cnt as countdown cursor (destroys it); packs (src, norm) into uint2
__global__ void fill_kernel(const int* __restrict__ src, const int* __restrict__ dst,
                            const int* __restrict__ off, int* __restrict__ cnt,
                            uint2* __restrict__ epack, const float* __restrict__ dis, int E) {
  int e = blockIdx.x * blockDim.x + threadIdx.x;
  if (e >= E) return;
  int s = src[e], d = dst[e];
  int slot = atomicSub(&cnt[d], 1) - 1;
  int p = off[d] + slot;
  uint2 v;
  v.x = (uint32)s;
  v.y = __float_as_uint(dis[s] * dis[d]);
  epack[p] = v;
}

// ---------------- W1/W2/W3 -> bf16 hi/lo in MFMA B-fragment order ----------

__global__ void wconv3_kernel(const float* __restrict__ W1, const float* __restrict__ W2,
                              const float* __restrict__ W3, ushort* __restrict__ Wf) {
  int idx = blockIdx.x * 256 + threadIdx.x;  // 0..98303
  int which = idx >> 15;
  int id = idx & 32767;
  const float* W = (which == 0) ? W1 : ((which == 1) ? W2 : W3);
  int j = id & 7;
  int l = (id >> 3) & 63;
  int f = id >> 9;
  int p = f & 1, kc = (f >> 1) & 3, ct = f >> 3;
  int k = kc * 32 + (l >> 4) * 8 + j;
  int col = ct * 16 + (l & 15);
  float w = W[k * D + col];
  ushort hi = bf16rne(w);
  ushort outv = hi;
  if (p) {
    float hf = __uint_as_float((uint32)hi << 16);
    outv = bf16rne(w - hf);
  }
  Wf[idx] = outv;
}

// ---------------- x (fp32) -> xb (bf16) ------------------------------------

__global__ void xb_kernel(const float* __restrict__ x, ushort* __restrict__ xb, int total4) {
  int i = blockIdx.x * 256 + threadIdx.x;
  if (i >= total4) return;
  float4 v = ((const float4*)x)[i];
  uint2 o;
  o.x = packbf2(v.x, v.y);
  o.y = packbf2(v.z, v.w);
  ((uint2*)xb)[i] = o;
}

// ------- fused layer: out = [relu](Agg(t) @ W + bias) ----------------------
// gather-first form (Agg commutes with @W). M=64 rows per block, 256 threads.
// 16-lane groups own rows; 4-deep edge pipeline for MLP.

template <int FINAL>
__global__ __launch_bounds__(256) void fused_kernel(const ushort* __restrict__ t,
                                                    const uint2* __restrict__ epack,
                                                    const int* __restrict__ off,
                                                    const float* __restrict__ dis,
                                                    const ushort* __restrict__ Wf,
                                                    const float* __restrict__ bias,
                                                    void* __restrict__ outp, int N) {
  __shared__ char lds[32768];
  int tid = threadIdx.x;
  int row0 = blockIdx.x * 64;
  int lane = tid & 63, wv = tid >> 6;
  int q = lane & 15, g = lane >> 4;
  const char* tb = (const char*)t;

#pragma unroll 1
  for (int n4 = 0; n4 < 4; n4++) {
    int r = wv * 16 + n4 * 4 + g;
    int node = row0 + r;
    float a[8];
#pragma unroll
    for (int i = 0; i < 8; i++) a[i] = 0.f;

    if (node < N) {
      int j0 = off[node], j1 = off[node + 1];
      int j = j0;
      for (; j + 4 <= j1; j += 4) {
        uint2 e0 = epack[j], e1 = epack[j + 1], e2 = epack[j + 2], e3 = epack[j + 3];
        uint4 h0 = *(const uint4*)(tb + (size_t)e0.x * 256 + q * 16);
        uint4 h1 = *(const uint4*)(tb + (size_t)e1.x * 256 + q * 16);
        uint4 h2 = *(const uint4*)(tb + (size_t)e2.x * 256 + q * 16);
        uint4 h3 = *(const uint4*)(tb + (size_t)e3.x * 256 + q * 16);
        acc8(a, __uint_as_float(e0.y), h0);
        acc8(a, __uint_as_float(e1.y), h1);
        acc8(a, __uint_as_float(e2.y), h2);
        acc8(a, __uint_as_float(e3.y), h3);
      }
      for (; j < j1; j++) {
        uint2 e0 = epack[j];
        uint4 h0 = *(const uint4*)(tb + (size_t)e0.x * 256 + q * 16);
        acc8(a, __uint_as_float(e0.y), h0);
      }
      float dsv = dis[node];
      float sw = dsv * dsv;  // self-loop norm
      uint4 hs = *(const uint4*)(tb + (size_t)node * 256 + q * 16);
      acc8(a, sw, hs);
    }
    uint4 pv;
    pv.x = packbf2(a[0], a[1]);
    pv.y = packbf2(a[2], a[3]);
    pv.z = packbf2(a[4], a[5]);
    pv.w = packbf2(a[6], a[7]);
    int boff = (r * 256 + q * 16) ^ ((r & 7) << 4);
    *(uint4*)(lds + boff) = pv;
  }
  __syncthreads();

  // ---- MFMA: z(64x128) @ W(128x128), W as hi+lo bf16 ----
  int lr = lane & 15, lg = lane >> 4;
  int m0 = wv * 16;

  bf16x8 af[4];
#pragma unroll
  for (int kc = 0; kc < 4; kc++) {
    int row = m0 + lr;
    int boff = (row * 256 + kc * 64 + lg * 16) ^ ((row & 7) << 4);
    af[kc] = *(bf16x8*)(lds + boff);
  }

  float bcol[8];
#pragma unroll
  for (int ct = 0; ct < 8; ct++) bcol[ct] = bias[ct * 16 + lr];

  f32x4 acc[8];
#pragma unroll
  for (int ct = 0; ct < 8; ct++) acc[ct] = (f32x4){0.f, 0.f, 0.f, 0.f};

#pragma unroll 1
  for (int ct = 0; ct < 8; ct++) {
    bf16x8 bf_[4][2];
#pragma unroll
    for (int kc = 0; kc < 4; kc++)
#pragma unroll
      for (int p = 0; p < 2; p++)
        bf_[kc][p] = *(const bf16x8*)&Wf[(size_t)((((ct * 4 + kc) * 2 + p) * 64 + lane) * 8)];
#pragma unroll
    for (int kc = 0; kc < 4; kc++) {
      acc[ct] = __builtin_amdgcn_mfma_f32_16x16x32_bf16(af[kc], bf_[kc][0], acc[ct], 0, 0, 0);
      acc[ct] = __builtin_amdgcn_mfma_f32_16x16x32_bf16(af[kc], bf_[kc][1], acc[ct], 0, 0, 0);
    }
  }
  __syncthreads();

  if (FINAL) {
    // fp32 epilogue via 32KB LDS bounce (C/D: col=lr, row=m0+lg*4+r)
#pragma unroll
    for (int ct = 0; ct < 8; ct++)
#pragma unroll
      for (int r = 0; r < 4; r++) {
        int row = m0 + lg * 4 + r;
        int col = ct * 16 + lr;
        float v = acc[ct][r] + bcol[ct];
        int boff = (row * 512 + col * 4) ^ ((row & 7) << 4);
        *(float*)(lds + boff) = v;
      }
    __syncthreads();
    float* out = (float*)outp;
#pragma unroll
    for (int i = 0; i < 8; i++) {
      int f = i * 4096 + tid * 16;
      int row = f >> 9;
      int boff = f ^ ((row & 7) << 4);
      if (row0 + row < N) {
        uint4 v = *(uint4*)(lds + boff);
        *(uint4*)((char*)out + (size_t)(row0 + row) * 512 + (f & 511)) = v;
      }
    }
  } else {
    // bf16 epilogue: bias + relu, 16KB LDS bounce
#pragma unroll
    for (int ct = 0; ct < 8; ct++)
#pragma unroll
      for (int r = 0; r < 4; r++) {
        int row = m0 + lg * 4 + r;
        int col = ct * 16 + lr;
        float v = fmaxf(acc[ct][r] + bcol[ct], 0.f);
        int boff = (row * 256 + col * 2) ^ ((row & 7) << 4);
        *(ushort*)(lds + boff) = bf16rne(v);
      }
    __syncthreads();
    ushort* outb = (ushort*)outp;
#pragma unroll
    for (int i = 0; i < 4; i++) {
      int f = i * 4096 + tid * 16;
      int row = f >> 8;
      int boff = f ^ ((row & 7) << 4);
      if (row0 + row < N) {
        uint4 v = *(uint4*)(lds + boff);
        *(uint4*)((char*)outb + (size_t)(row0 + row) * 256 + (f & 255)) = v;
      }
    }
  }
}

// ---------------- launch ----------------

extern "C" void kernel_launch(void* const* d_in, const int* in_sizes, int n_in,
                              void* d_out, int out_size, void* d_ws, size_t ws_size,
                              hipStream_t stream) {
  const float* x  = (const float*)d_in[0];
  const int*   ei = (const int*)d_in[1];
  const float* W1 = (const float*)d_in[2];
  const float* b1 = (const float*)d_in[3];
  const float* W2 = (const float*)d_in[4];
  const float* b2 = (const float*)d_in[5];
  const float* W3 = (const float*)d_in[6];
  const float* b3 = (const float*)d_in[7];
  int N = in_sizes[0] / D;
  int E = in_sizes[1] / 2;
  const int* srcp = ei;
  const int* dstp = ei + E;

  char* wp = (char*)d_ws;
  auto carve = [&](size_t bytes) {
    void* p = (void*)wp;
    wp += (bytes + 255) & ~(size_t)255;
    return p;
  };
  int*    cnt   = (int*)carve((size_t)N * 4);
  int*    off   = (int*)carve((size_t)(N + 1) * 4);
  int*    bsum  = (int*)carve(256 * 4);
  float*  dis   = (float*)carve((size_t)N * 4);
  uint2*  epack = (uint2*)carve((size_t)E * 8);
  ushort* xb    = (ushort*)carve((size_t)N * D * 2);
  ushort* t1    = (ushort*)carve((size_t)N * D * 2);
  ushort* t2    = (ushort*)carve((size_t)N * D * 2);
  ushort* wfall = (ushort*)carve((size_t)3 * 32768 * 2);
  ushort* wf1 = wfall, *wf2 = wfall + 32768, *wf3 = wfall + 65536;

  hipMemsetAsync(cnt, 0, (size_t)N * 4, stream);

  const int tb = 256;
  wconv3_kernel<<<384, 256, 0, stream>>>(W1, W2, W3, wfall);
  xb_kernel<<<(N * D / 4 + 255) / 256, 256, 0, stream>>>(x, xb, N * D / 4);
  count_kernel<<<(E + tb - 1) / tb, tb, 0, stream>>>(dstp, cnt, E);
  int nb = (N + SCHUNK - 1) / SCHUNK;
  scan1_kernel<<<nb, SB, 0, stream>>>(cnt, off, bsum, dis, N);
  scan2_kernel<<<1, 64, 0, stream>>>(bsum, nb);
  scan3_kernel<<<(N + tb - 1) / tb, tb, 0, stream>>>(off, bsum, N, E);
  fill_kernel<<<(E + tb - 1) / tb, tb, 0, stream>>>(srcp, dstp, off, cnt, epack, dis, E);

  int fb = (N + 63) / 64;
  fused_kernel<0><<<fb, 256, 0, stream>>>(xb, epack, off, dis, wf1, b1, t1, N);
  fused_kernel<0><<<fb, 256, 0, stream>>>(t1, epack, off, dis, wf2, b2, t2, N);
  fused_kernel<1><<<fb, 256, 0, stream>>>(t2, epack, off, dis, wf3, b3, d_out, N);
}

// Round 6
// 232.706 us; speedup vs baseline: 3.8596x; 1.1313x over previous
//
#include <hip/hip_runtime.h>

#define D 128
#define SB 256
#define SI 8
#define SCHUNK (SB * SI)

typedef __attribute__((ext_vector_type(8))) short bf16x8;
typedef __attribute__((ext_vector_type(4))) float f32x4;
typedef unsigned int uint32;
typedef unsigned short ushort;

__device__ __forceinline__ ushort bf16rne(float f) {
  uint32 u = __float_as_uint(f);
  uint32 r = u + 0x7FFFu + ((u >> 16) & 1u);
  return (ushort)(r >> 16);
}
__device__ __forceinline__ float bf2f_lo(uint32 h) { return __uint_as_float(h << 16); }
__device__ __forceinline__ float bf2f_hi(uint32 h) { return __uint_as_float(h & 0xFFFF0000u); }
__device__ __forceinline__ uint32 packbf2(float x, float y) {
  return (uint32)bf16rne(x) | ((uint32)bf16rne(y) << 16);
}
__device__ __forceinline__ void acc8(float* a, float w, uint4 h) {
  a[0] += w * bf2f_lo(h.x); a[1] += w * bf2f_hi(h.x);
  a[2] += w * bf2f_lo(h.y); a[3] += w * bf2f_hi(h.y);
  a[4] += w * bf2f_lo(h.z); a[5] += w * bf2f_hi(h.z);
  a[6] += w * bf2f_lo(h.w); a[7] += w * bf2f_hi(h.w);
}

// ---------------- prep: xb convert + degree count + W-conv, one launch -----

__global__ void prep_kernel(const float* __restrict__ x, ushort* __restrict__ xb, int total4,
                            const int* __restrict__ dst, int* __restrict__ cnt, int E,
                            const float* __restrict__ W1, const float* __restrict__ W2,
                            const float* __restrict__ W3, ushort* __restrict__ Wf,
                            int xbB, int cntB) {
  int b = blockIdx.x;
  int tid = threadIdx.x;
  if (b < xbB) {
    int i = b * 256 + tid;
    if (i < total4) {
      float4 v = ((const float4*)x)[i];
      uint2 o;
      o.x = packbf2(v.x, v.y);
      o.y = packbf2(v.z, v.w);
      ((uint2*)xb)[i] = o;
    }
  } else if (b < xbB + cntB) {
    int e = (b - xbB) * 256 + tid;
    if (e < E) atomicAdd(&cnt[dst[e]], 1);
  } else {
    int idx = (b - xbB - cntB) * 256 + tid;  // 0..98303
    int which = idx >> 15;
    int id = idx & 32767;
    const float* W = (which == 0) ? W1 : ((which == 1) ? W2 : W3);
    int j = id & 7;
    int l = (id >> 3) & 63;
    int f = id >> 9;
    int p = f & 1, kc = (f >> 1) & 3, ct = f >> 3;
    int k = kc * 32 + (l >> 4) * 8 + j;
    int col = ct * 16 + (l & 15);
    float w = W[k * D + col];
    ushort hi = bf16rne(w);
    ushort outv = hi;
    if (p) {
      float hf = __uint_as_float((uint32)hi << 16);
      outv = bf16rne(w - hf);
    }
    Wf[idx] = outv;
  }
}

// ---------------- CSR build ----------------

__global__ void scan1_kernel(const int* __restrict__ cnt, int* __restrict__ off,
                             int* __restrict__ bsum, float* __restrict__ dis, int n) {
  __shared__ int tsum[SB];
  int tid = threadIdx.x;
  int base = blockIdx.x * SCHUNK;
  int v[SI];
  int s = 0;
#pragma unroll
  for (int i = 0; i < SI; i++) {
    int idx = base + tid * SI + i;
    v[i] = (idx < n) ? cnt[idx] : 0;
    s += v[i];
  }
  tsum[tid] = s;
  __syncthreads();
  for (int o = 1; o < SB; o <<= 1) {
    int t = (tid >= o) ? tsum[tid - o] : 0;
    __syncthreads();
    tsum[tid] += t;
    __syncthreads();
  }
  int run = tsum[tid] - s;
#pragma unroll
  for (int i = 0; i < SI; i++) {
    int idx = base + tid * SI + i;
    if (idx < n) {
      off[idx] = run;
      dis[idx] = rsqrtf((float)(v[i] + 1));
    }
    run += v[i];
  }
  if (tid == SB - 1) bsum[blockIdx.x] = tsum[tid];
}

__global__ void scan2_kernel(int* bsum, int nb) {
  if (threadIdx.x == 0 && blockIdx.x == 0) {
    int run = 0;
    for (int b = 0; b < nb; b++) { int t = bsum[b]; bsum[b] = run; run += t; }
  }
}

__global__ void scan3_kernel(int* __restrict__ off, const int* __restrict__ bsum,
                             int n, int total) {
  int i = blockIdx.x * blockDim.x + threadIdx.x;
  if (i < n) off[i] += bsum[i / SCHUNK];
  if (i == 0) off[n] = total;
}

// fill: uses cnt as countdown cursor (destroys it); packs (src, norm)
__global__ void fill_kernel(const int* __restrict__ src, const int* __restrict__ dst,
                            const int* __restrict__ off, int* __restrict__ cnt,
                            uint2* __restrict__ epack, const float* __restrict__ dis, int E) {
  int e = blockIdx.x * blockDim.x + threadIdx.x;
  if (e >= E) return;
  int s = src[e], d = dst[e];
  int slot = atomicSub(&cnt[d], 1) - 1;
  int p = off[d] + slot;
  uint2 v;
  v.x = (uint32)s;
  v.y = __float_as_uint(dis[s] * dis[d]);
  epack[p] = v;
}

// ------- fused layer: out = [relu](Agg(t) @ W + bias) ----------------------
// gather-first (Agg commutes with @W). M=64 rows/block, 16KB LDS.

template <int FINAL>
__global__ __launch_bounds__(256, 4) void fused_kernel(const ushort* __restrict__ t,
                                                       const uint2* __restrict__ epack,
                                                       const int* __restrict__ off,
                                                       const float* __restrict__ dis,
                                                       const ushort* __restrict__ Wf,
                                                       const float* __restrict__ bias,
                                                       void* __restrict__ outp, int N) {
  __shared__ char lds[16384];
  int tid = threadIdx.x;
  int row0 = blockIdx.x * 64;
  int lane = tid & 63, wv = tid >> 6;
  int q = lane & 15, g = lane >> 4;
  int qb = q * 16;
  const char* tb = (const char*)t;

#pragma unroll 1
  for (int n4 = 0; n4 < 4; n4++) {
    int r = wv * 16 + n4 * 4 + g;
    int node = row0 + r;
    float a[8];
#pragma unroll
    for (int i = 0; i < 8; i++) a[i] = 0.f;

    if (node < N) {
      // self-loop load first (independent of edge list)
      uint32 soff = ((uint32)node << 8) + qb;
      uint4 hs = *(const uint4*)(tb + soff);
      int j0 = off[node], j1 = off[node + 1];
      float dsv = dis[node];
      float sw = dsv * dsv;

      auto ldE = [&](int idx) -> uint2 {
        if (idx < j1) return epack[idx];
        uint2 z; z.x = (uint32)node; z.y = 0u; return z;
      };
      int j = j0;
      uint2 e0 = ldE(j), e1 = ldE(j + 1), e2 = ldE(j + 2), e3 = ldE(j + 3);
      while (j < j1) {
        uint4 h0 = *(const uint4*)(tb + ((e0.x << 8) + qb));
        uint4 h1 = *(const uint4*)(tb + ((e1.x << 8) + qb));
        uint4 h2 = *(const uint4*)(tb + ((e2.x << 8) + qb));
        uint4 h3 = *(const uint4*)(tb + ((e3.x << 8) + qb));
        float w0 = __uint_as_float(e0.y), w1 = __uint_as_float(e1.y);
        float w2 = __uint_as_float(e2.y), w3 = __uint_as_float(e3.y);
        int jn = j + 4;
        e0 = ldE(jn); e1 = ldE(jn + 1); e2 = ldE(jn + 2); e3 = ldE(jn + 3);
        acc8(a, w0, h0);
        acc8(a, w1, h1);
        acc8(a, w2, h2);
        acc8(a, w3, h3);
        j = jn;
      }
      acc8(a, sw, hs);
    }
    uint4 pv;
    pv.x = packbf2(a[0], a[1]);
    pv.y = packbf2(a[2], a[3]);
    pv.z = packbf2(a[4], a[5]);
    pv.w = packbf2(a[6], a[7]);
    int boff = (r * 256 + qb) ^ ((r & 7) << 4);
    *(uint4*)(lds + boff) = pv;
  }
  __syncthreads();

  // ---- MFMA: z(64x128) @ W(128x128), W as hi+lo bf16 ----
  int lr = lane & 15, lg = lane >> 4;
  int m0 = wv * 16;

  bf16x8 af[4];
#pragma unroll
  for (int kc = 0; kc < 4; kc++) {
    int row = m0 + lr;
    int boff = (row * 256 + kc * 64 + lg * 16) ^ ((row & 7) << 4);
    af[kc] = *(bf16x8*)(lds + boff);
  }

  float bcol[8];
#pragma unroll
  for (int ct = 0; ct < 8; ct++) bcol[ct] = bias[ct * 16 + lr];

  f32x4 acc[8];
#pragma unroll
  for (int ct = 0; ct < 8; ct++) acc[ct] = (f32x4){0.f, 0.f, 0.f, 0.f};

#pragma unroll 1
  for (int ct = 0; ct < 8; ct++) {
    bf16x8 bf_[4][2];
#pragma unroll
    for (int kc = 0; kc < 4; kc++)
#pragma unroll
      for (int p = 0; p < 2; p++)
        bf_[kc][p] = *(const bf16x8*)&Wf[(size_t)((((ct * 4 + kc) * 2 + p) * 64 + lane) * 8)];
#pragma unroll
    for (int kc = 0; kc < 4; kc++) {
      acc[ct] = __builtin_amdgcn_mfma_f32_16x16x32_bf16(af[kc], bf_[kc][0], acc[ct], 0, 0, 0);
      acc[ct] = __builtin_amdgcn_mfma_f32_16x16x32_bf16(af[kc], bf_[kc][1], acc[ct], 0, 0, 0);
    }
  }
  __syncthreads();

  if (FINAL) {
    // fp32 epilogue: two 64-column passes through 16KB LDS
    float* out = (float*)outp;
#pragma unroll
    for (int p = 0; p < 2; p++) {
#pragma unroll
      for (int c4 = 0; c4 < 4; c4++) {
        int ct = p * 4 + c4;
#pragma unroll
        for (int r = 0; r < 4; r++) {
          int row = m0 + lg * 4 + r;
          int colb = c4 * 16 + lr;  // 0..63 within pass
          float v = acc[ct][r] + bcol[ct];
          int boff = (row * 256 + colb * 4) ^ ((row & 7) << 4);
          *(float*)(lds + boff) = v;
        }
      }
      __syncthreads();
#pragma unroll
      for (int i = 0; i < 4; i++) {
        int f = i * 4096 + tid * 16;
        int row = f >> 8;
        int boff = f ^ ((row & 7) << 4);
        if (row0 + row < N) {
          uint4 v = *(uint4*)(lds + boff);
          *(uint4*)((char*)out + (size_t)(row0 + row) * 512 + p * 256 + (f & 255)) = v;
        }
      }
      if (p == 0) __syncthreads();
    }
  } else {
    // bf16 epilogue: bias + relu through 16KB LDS
#pragma unroll
    for (int ct = 0; ct < 8; ct++)
#pragma unroll
      for (int r = 0; r < 4; r++) {
        int row = m0 + lg * 4 + r;
        int col = ct * 16 + lr;
        float v = fmaxf(acc[ct][r] + bcol[ct], 0.f);
        int boff = (row * 256 + col * 2) ^ ((row & 7) << 4);
        *(ushort*)(lds + boff) = bf16rne(v);
      }
    __syncthreads();
    ushort* outb = (ushort*)outp;
#pragma unroll
    for (int i = 0; i < 4; i++) {
      int f = i * 4096 + tid * 16;
      int row = f >> 8;
      int boff = f ^ ((row & 7) << 4);
      if (row0 + row < N) {
        uint4 v = *(uint4*)(lds + boff);
        *(uint4*)((char*)outb + (size_t)(row0 + row) * 256 + (f & 255)) = v;
      }
    }
  }
}

// ---------------- launch ----------------

extern "C" void kernel_launch(void* const* d_in, const int* in_sizes, int n_in,
                              void* d_out, int out_size, void* d_ws, size_t ws_size,
                              hipStream_t stream) {
  const float* x  = (const float*)d_in[0];
  const int*   ei = (const int*)d_in[1];
  const float* W1 = (const float*)d_in[2];
  const float* b1 = (const float*)d_in[3];
  const float* W2 = (const float*)d_in[4];
  const float* b2 = (const float*)d_in[5];
  const float* W3 = (const float*)d_in[6];
  const float* b3 = (const float*)d_in[7];
  int N = in_sizes[0] / D;
  int E = in_sizes[1] / 2;
  const int* srcp = ei;
  const int* dstp = ei + E;

  char* wp = (char*)d_ws;
  auto carve = [&](size_t bytes) {
    void* p = (void*)wp;
    wp += (bytes + 255) & ~(size_t)255;
    return p;
  };
  int*    cnt   = (int*)carve((size_t)N * 4);
  int*    off   = (int*)carve((size_t)(N + 1) * 4);
  int*    bsum  = (int*)carve(256 * 4);
  float*  dis   = (float*)carve((size_t)N * 4);
  uint2*  epack = (uint2*)carve((size_t)E * 8);
  ushort* xb    = (ushort*)carve((size_t)N * D * 2);
  ushort* t1    = (ushort*)carve((size_t)N * D * 2);
  ushort* t2    = (ushort*)carve((size_t)N * D * 2);
  ushort* wfall = (ushort*)carve((size_t)3 * 32768 * 2);
  ushort* wf1 = wfall, *wf2 = wfall + 32768, *wf3 = wfall + 65536;

  hipMemsetAsync(cnt, 0, (size_t)N * 4, stream);

  const int tb = 256;
  int total4 = N * D / 4;
  int xbB = (total4 + 255) / 256;
  int cntB = (E + 255) / 256;
  prep_kernel<<<xbB + cntB + 384, 256, 0, stream>>>(x, xb, total4, dstp, cnt, E,
                                                    W1, W2, W3, wfall, xbB, cntB);
  int nb = (N + SCHUNK - 1) / SCHUNK;
  scan1_kernel<<<nb, SB, 0, stream>>>(cnt, off, bsum, dis, N);
  scan2_kernel<<<1, 64, 0, stream>>>(bsum, nb);
  scan3_kernel<<<(N + tb - 1) / tb, tb, 0, stream>>>(off, bsum, N, E);
  fill_kernel<<<(E + tb - 1) / tb, tb, 0, stream>>>(srcp, dstp, off, cnt, epack, dis, E);

  int fb = (N + 63) / 64;
  fused_kernel<0><<<fb, 256, 0, stream>>>(xb, epack, off, dis, wf1, b1, t1, N);
  fused_kernel<0><<<fb, 256, 0, stream>>>(t1, epack, off, dis, wf2, b2, t2, N);
  fused_kernel<1><<<fb, 256, 0, stream>>>(t2, epack, off, dis, wf3, b3, d_out, N);
}